// Round 5
// baseline (389.502 us; speedup 1.0000x reference)
//
#include <hip/hip_runtime.h>
#include <math.h>

// Problem dims (fixed)
constexpr int H_ = 1024;
constexpr int I_ = 2816;
constexpr int E_ = 8;
constexpr int T_ = 1024;   // S*B tokens

typedef __bf16 bf16x8 __attribute__((ext_vector_type(8)));
typedef float f32x4 __attribute__((ext_vector_type(4)));

__device__ __forceinline__ ushort f2bf(float f) {
    uint32_t u = __float_as_uint(f);
    u += 0x7fff + ((u >> 16) & 1);   // round-to-nearest-even
    return (ushort)(u >> 16);
}
__device__ __forceinline__ uint pack2(float lo, float hi) {
    return (uint)f2bf(lo) | ((uint)f2bf(hi) << 16);
}
// fp32x8 -> bf16x8 via v_cvt_pk_bf16_f32 (RNE, gfx950).
__device__ __forceinline__ bf16x8 cvt8pk(float4 a, float4 b) {
    union { uint u[4]; bf16x8 v; } r;
    asm("v_cvt_pk_bf16_f32 %0, %1, %2" : "=v"(r.u[0]) : "v"(a.x), "v"(a.y));
    asm("v_cvt_pk_bf16_f32 %0, %1, %2" : "=v"(r.u[1]) : "v"(a.z), "v"(a.w));
    asm("v_cvt_pk_bf16_f32 %0, %1, %2" : "=v"(r.u[2]) : "v"(b.x), "v"(b.y));
    asm("v_cvt_pk_bf16_f32 %0, %1, %2" : "=v"(r.u[3]) : "v"(b.z), "v"(b.w));
    return r.v;
}

// async global->LDS, 16B per lane; LDS dest = wave-uniform base + lane*16 (HW).
__device__ __forceinline__ void async_copy16(void* lds, const void* g) {
    __builtin_amdgcn_global_load_lds(
        (const __attribute__((address_space(1))) void*)g,
        (__attribute__((address_space(3))) void*)lds, 16, 0, 0);
}

// ws layout: int counts[8]; int tlist[8*1024]; ushort xbf[1024*1024]; ushort act[1024*2816]

__global__ __launch_bounds__(64) void router_kernel(const float* __restrict__ hidden,
                                                    const float* __restrict__ rw,
                                                    int* __restrict__ counts,
                                                    int* __restrict__ tlist,
                                                    ushort* __restrict__ xbf) {
    const int t = blockIdx.x;
    const int lane = threadIdx.x;
    const float* x = hidden + (size_t)t * H_ + lane * 16;
    float4 v[4];
#pragma unroll
    for (int j = 0; j < 4; j++) v[j] = ((const float4*)x)[j];
    uint2* xb = (uint2*)(xbf + (size_t)t * H_ + lane * 16);
#pragma unroll
    for (int j = 0; j < 4; j++) xb[j] = make_uint2(pack2(v[j].x, v[j].y), pack2(v[j].z, v[j].w));
    float acc[E_];
#pragma unroll
    for (int e = 0; e < E_; e++) {
        const float4* r = (const float4*)(rw + e * H_ + lane * 16);
        float a = 0.f;
#pragma unroll
        for (int j = 0; j < 4; j++) {
            float4 rv = r[j];
            a += v[j].x * rv.x + v[j].y * rv.y + v[j].z * rv.z + v[j].w * rv.w;
        }
        acc[e] = a;
    }
#pragma unroll
    for (int e = 0; e < E_; e++) {
#pragma unroll
        for (int off = 32; off >= 1; off >>= 1)
            acc[e] += __shfl_xor(acc[e], off, 64);
    }
    if (lane == 0) {
        int best = 0;
        float bv = acc[0];
#pragma unroll
        for (int e = 1; e < E_; e++) {
            if (acc[e] > bv) { bv = acc[e]; best = e; }  // strict > : first max wins
        }
        int pos = atomicAdd(&counts[best], 1);
        tlist[best * T_ + pos] = t;
    }
}

// Phase A: per expert e (e=id&7 -> XCD-pinned), 32 I-rows, M=256 tokens, BK=32.
// ALL staging via global_load_lds (zero VGPR in-flight cost), depth-3 buffers,
// one barrier/iter, counted vmcnt(6) = exactly S(t+1)'s ops -> S(t) cover ~2 iters.
// XOR-swizzled sources (linear LDS dest) -> <=2-way ds_read conflicts.
__global__ __launch_bounds__(256, 2) void gateup_kernel(const ushort* __restrict__ xbf,
                                                        const float* __restrict__ gate_w,
                                                        const float* __restrict__ up_w,
                                                        const int* __restrict__ counts,
                                                        const int* __restrict__ tlist,
                                                        ushort* __restrict__ act) {
    const int id = blockIdx.x;
    const int e  = id & 7;
    const int i0 = (id >> 3) * 32;
    const int cnt = counts[e];
    const int tid = threadIdx.x;
    const int wv = tid >> 6, lane = tid & 63, quad = lane >> 4, l15 = lane & 15;

    __shared__ ushort Xs[3 * 8192];   // 3 bufs x 256 rows x 64B (swizzled chunks)
    __shared__ float  Gs[3 * 1024];   // 3 bufs x 32 rows x 128B
    __shared__ float  Us[3 * 1024];
    __shared__ int toks[256];

    // weight stage (chunk-invariant): row rg, 16B chunk (lane&7)^ (rg&7)
    const int rg = wv * 8 + (lane >> 3);
    const int cg = ((lane & 7) ^ (rg & 7)) << 2;       // float offset
    const float* gsp = gate_w + ((size_t)e * I_ + i0 + rg) * H_ + cg;
    const float* usp = up_w   + ((size_t)e * I_ + i0 + rg) * H_ + cg;
    const int wdstF = wv * 256 + lane * 4;             // float offset in buffer

    for (int toff = 0; toff < cnt; toff += 256) {
        __syncthreads();
        { int p = toff + tid; toks[tid] = (p < cnt) ? tlist[e * T_ + p] : -1; }
        __syncthreads();

        const ushort* xsp[4];
        int xdst[4];
#pragma unroll
        for (int p = 0; p < 4; p++) {
            int rp = wv * 64 + p * 16 + (lane >> 2);
            int tok = toks[rp]; if (tok < 0) tok = 0;
            int q = (lane & 3) ^ ((rp >> 1) & 3);      // source 16B chunk (involution)
            xsp[p] = xbf + (size_t)tok * H_ + q * 8;
            xdst[p] = wv * 2048 + p * 512 + lane * 8;  // ushort offset in buffer
        }

        f32x4 accg[4][2], accu[4][2];
#pragma unroll
        for (int mi = 0; mi < 4; mi++)
#pragma unroll
            for (int nj = 0; nj < 2; nj++) {
                accg[mi][nj] = (f32x4){0.f, 0.f, 0.f, 0.f};
                accu[mi][nj] = (f32x4){0.f, 0.f, 0.f, 0.f};
            }

#define GSTAGE(b, k) do {                                                       \
        _Pragma("unroll")                                                       \
        for (int p = 0; p < 4; p++)                                             \
            async_copy16(&Xs[(b) * 8192 + xdst[p]], xsp[p] + (k));              \
        async_copy16(&Gs[(b) * 1024 + wdstF], gsp + (k));                       \
        async_copy16(&Us[(b) * 1024 + wdstF], usp + (k));                       \
    } while (0)

        GSTAGE(0, 0);
        GSTAGE(1, 32);
        int cur = 0, sb = 2;
#pragma unroll 1
        for (int t = 0; t < 32; ++t) {
            if (t < 31) asm volatile("s_waitcnt vmcnt(6)" ::: "memory");
            else        asm volatile("s_waitcnt vmcnt(0)" ::: "memory");
            __builtin_amdgcn_sched_barrier(0);
            __builtin_amdgcn_s_barrier();
            __builtin_amdgcn_sched_barrier(0);
            if (t < 30) { GSTAGE(sb, t * 32 + 64); __builtin_amdgcn_sched_barrier(0); }

            const ushort* Xb = &Xs[cur * 8192];
            const float*  Gb = &Gs[cur * 1024];
            const float*  Ub = &Us[cur * 1024];
            bf16x8 a[4], bg[2], bu[2];
#pragma unroll
            for (int nj = 0; nj < 2; nj++) {
                int rr = nj * 16 + l15;
                int c0 = (2 * quad) ^ (rr & 7), c1 = (2 * quad + 1) ^ (rr & 7);
                bg[nj] = cvt8pk(*(const float4*)(Gb + rr * 32 + c0 * 4),
                                *(const float4*)(Gb + rr * 32 + c1 * 4));
                bu[nj] = cvt8pk(*(const float4*)(Ub + rr * 32 + c0 * 4),
                                *(const float4*)(Ub + rr * 32 + c1 * 4));
            }
#pragma unroll
            for (int mi = 0; mi < 4; mi++) {
                int r = wv * 64 + mi * 16 + l15;
                int qq = quad ^ ((r >> 1) & 3);
                a[mi] = *(const bf16x8*)(Xb + r * 32 + qq * 8);
            }
#pragma unroll
            for (int mi = 0; mi < 4; mi++)
#pragma unroll
                for (int nj = 0; nj < 2; nj++) {
                    accg[mi][nj] = __builtin_amdgcn_mfma_f32_16x16x32_bf16(a[mi], bg[nj], accg[mi][nj], 0, 0, 0);
                    accu[mi][nj] = __builtin_amdgcn_mfma_f32_16x16x32_bf16(a[mi], bu[nj], accu[mi][nj], 0, 0, 0);
                }
            __builtin_amdgcn_sched_barrier(0);
            cur = (cur == 2) ? 0 : cur + 1;
            sb  = (sb  == 2) ? 0 : sb  + 1;
        }
#undef GSTAGE

#pragma unroll
        for (int mi = 0; mi < 4; mi++)
#pragma unroll
            for (int r = 0; r < 4; r++) {
                int tok = toks[wv * 64 + mi * 16 + quad * 4 + r];
                if (tok < 0) continue;
#pragma unroll
                for (int nj = 0; nj < 2; nj++) {
                    float g = accg[mi][nj][r], u = accu[mi][nj][r];
                    float s = g / (1.f + __expf(-g)) * u;
                    act[(size_t)tok * I_ + i0 + nj * 16 + l15] = f2bf(s);
                }
            }
    }
}

// Phase B: per expert e, 16 H-rows (grid 64x8=512 -> 2 blocks/CU, all resident),
// M=256 tokens, full K=I=2816, BK=32, depth-3 global_load_lds pipeline.
__global__ __launch_bounds__(256, 2) void down_kernel(const ushort* __restrict__ act,
                                                      const float* __restrict__ down_w,
                                                      const int* __restrict__ counts,
                                                      const int* __restrict__ tlist,
                                                      float* __restrict__ out) {
    const int id = blockIdx.x;
    const int e  = id & 7;
    const int h0 = (id >> 3) * 16;
    const int cnt = counts[e];
    const int tid = threadIdx.x;
    const int wv = tid >> 6, lane = tid & 63, quad = lane >> 4, l15 = lane & 15;

    __shared__ ushort As[3 * 8192];   // 3 bufs x 256 rows x 64B
    __shared__ float  Ws[3 * 512];    // 3 bufs x 16 rows x 128B (staged by waves 0,1)
    __shared__ int toks[256];

    const int rw_ = (wv & 1) * 8 + (lane >> 3);        // valid for wv<2 (the stagers)
    const int cw  = ((lane & 7) ^ (rw_ & 7)) << 2;
    const float* wsp = down_w + ((size_t)e * H_ + h0 + rw_) * I_ + cw;
    const int ddstF = (wv & 1) * 256 + lane * 4;

    for (int toff = 0; toff < cnt; toff += 256) {
        __syncthreads();
        { int p = toff + tid; toks[tid] = (p < cnt) ? tlist[e * T_ + p] : -1; }
        __syncthreads();

        const ushort* asp[4];
        int adst[4];
#pragma unroll
        for (int p = 0; p < 4; p++) {
            int rp = wv * 64 + p * 16 + (lane >> 2);
            int tok = toks[rp]; if (tok < 0) tok = 0;
            int q = (lane & 3) ^ ((rp >> 1) & 3);
            asp[p] = act + (size_t)tok * I_ + q * 8;
            adst[p] = wv * 2048 + p * 512 + lane * 8;
        }

        f32x4 acc[4];
#pragma unroll
        for (int mi = 0; mi < 4; mi++) acc[mi] = (f32x4){0.f, 0.f, 0.f, 0.f};

#define DSTAGE(b, k) do {                                                       \
        _Pragma("unroll")                                                       \
        for (int p = 0; p < 4; p++)                                             \
            async_copy16(&As[(b) * 8192 + adst[p]], asp[p] + (k));              \
        if (wv < 2)                                                             \
            async_copy16(&Ws[(b) * 512 + ddstF], wsp + (k));                    \
    } while (0)

        DSTAGE(0, 0);
        DSTAGE(1, 32);
        int cur = 0, sb = 2;
#pragma unroll 1
        for (int t = 0; t < 88; ++t) {
            if (t < 87) {
                if (wv < 2) asm volatile("s_waitcnt vmcnt(5)" ::: "memory");
                else        asm volatile("s_waitcnt vmcnt(4)" ::: "memory");
            } else {
                asm volatile("s_waitcnt vmcnt(0)" ::: "memory");
            }
            __builtin_amdgcn_sched_barrier(0);
            __builtin_amdgcn_s_barrier();
            __builtin_amdgcn_sched_barrier(0);
            if (t < 86) { DSTAGE(sb, t * 32 + 64); __builtin_amdgcn_sched_barrier(0); }

            const ushort* Ab = &As[cur * 8192];
            const float*  Wb = &Ws[cur * 512];
            bf16x8 a[4];
            {
                int rr = l15;
                int c0 = (2 * quad) ^ (rr & 7), c1 = (2 * quad + 1) ^ (rr & 7);
                bf16x8 bd = cvt8pk(*(const float4*)(Wb + rr * 32 + c0 * 4),
                                   *(const float4*)(Wb + rr * 32 + c1 * 4));
#pragma unroll
                for (int mi = 0; mi < 4; mi++) {
                    int r = wv * 64 + mi * 16 + l15;
                    int qq = quad ^ ((r >> 1) & 3);
                    a[mi] = *(const bf16x8*)(Ab + r * 32 + qq * 8);
                }
#pragma unroll
                for (int mi = 0; mi < 4; mi++)
                    acc[mi] = __builtin_amdgcn_mfma_f32_16x16x32_bf16(a[mi], bd, acc[mi], 0, 0, 0);
            }
            __builtin_amdgcn_sched_barrier(0);
            cur = (cur == 2) ? 0 : cur + 1;
            sb  = (sb  == 2) ? 0 : sb  + 1;
        }
#undef DSTAGE

#pragma unroll
        for (int mi = 0; mi < 4; mi++)
#pragma unroll
            for (int r = 0; r < 4; r++) {
                int tok = toks[wv * 64 + mi * 16 + quad * 4 + r];
                if (tok < 0) continue;
                out[(size_t)tok * H_ + h0 + l15] = acc[mi][r];
            }
    }
}

extern "C" void kernel_launch(void* const* d_in, const int* in_sizes, int n_in,
                              void* d_out, int out_size, void* d_ws, size_t ws_size,
                              hipStream_t stream) {
    const float* hidden = (const float*)d_in[0];
    const float* rw     = (const float*)d_in[1];
    const float* gate_w = (const float*)d_in[2];
    const float* up_w   = (const float*)d_in[3];
    const float* down_w = (const float*)d_in[4];
    float* out = (float*)d_out;

    int* counts = (int*)d_ws;
    int* tlist  = counts + E_;
    ushort* xbf = (ushort*)(tlist + E_ * T_);          // 2 MB
    ushort* act = xbf + (size_t)T_ * H_;               // 5.77 MB

    hipMemsetAsync(counts, 0, E_ * sizeof(int), stream);
    hipLaunchKernelGGL(router_kernel, dim3(T_), dim3(64), 0, stream, hidden, rw, counts, tlist, xbf);
    hipLaunchKernelGGL(gateup_kernel, dim3((I_ / 32) * E_), dim3(256), 0, stream,
                       xbf, gate_w, up_w, counts, tlist, act);
    hipLaunchKernelGGL(down_kernel, dim3((H_ / 16) * E_), dim3(256), 0, stream,
                       act, down_w, counts, tlist, out);
}